// Round 12
// baseline (796.871 us; speedup 1.0000x reference)
//
#include <hip/hip_runtime.h>
#include <math.h>

#define MT 16384          // B*N rows
#define DD 768
#define AW_OFF ((size_t)8 * MT * DD)

typedef __attribute__((ext_vector_type(8))) short short8;
typedef __attribute__((ext_vector_type(4))) float f32x4;
typedef __attribute__((ext_vector_type(4))) float fv4;
typedef __attribute__((ext_vector_type(4))) unsigned int u32x4;

// ---- workspace offsets (bytes) ----
#define OFF_W1T 0ULL                    // 8*768*768*2 = 9,437,184
#define OFF_W2T 9437184ULL              // 8*768*768*2 = 9,437,184
#define OFF_Z1  19660800ULL             // 8*MT*768*2  = 201,326,592
#define OFF_Z2  220987392ULL            // 4*MT*768*2  = 100,663,296
#define OFF_P1  321650688ULL            // 3*131072*8  = 3,145,728
#define OFF_P2  327942144ULL            // 3*65536*8   = 1,572,864
#define OFF_ST1 331087872ULL            // 131072*8    = 1,048,576
#define OFF_ST2 332136448ULL            // 65536*8     = 524,288
#define OFF_GP  332660736ULL            // 16*8*768*4  = 393,216
#define OFF_GM  333053952ULL            // 16*768*4    = 49,152
#define OFF_CXF 333103104ULL            // 2*16*64*4   = 8,192
#define OFF_B1X 333111296ULL            // 8*16*768*4  = 393,216
#define OFF_A1  335544320ULL            // 8*MT*768*2  = 201,326,592 (ends 512MB)

static __device__ __forceinline__ unsigned short f2bf(float f) {
  unsigned u = __float_as_uint(f);
  u += 0x7fffu + ((u >> 16) & 1u);
  return (unsigned short)(u >> 16);
}
static __device__ __forceinline__ float bf2f(unsigned short h) {
  return __uint_as_float(((unsigned)h) << 16);
}
static __device__ __forceinline__ unsigned pk2(float lo, float hi) {
  return (unsigned)f2bf(lo) | ((unsigned)f2bf(hi) << 16);
}
static __device__ __forceinline__ float gelu_t(float y) {
  float y2 = y * y;
  float c = fmaf(y2, 0.0713548163f, 1.59576912161f);
  float e = __expf(-y * c);
  return y / (1.0f + e);
}
static __device__ __forceinline__ void gload_lds16(const void* g, void* l) {
  __builtin_amdgcn_global_load_lds(
      (const __attribute__((address_space(1))) void*)g,
      (__attribute__((address_space(3))) void*)l, 16, 0, 0);
}

// ---------------------------------------------------------------- transpose
__global__ void transpose_cvt(const float* sw1, const float* rw1,
                              const float* sw2, const float* rw2,
                              unsigned short* w1T, unsigned short* w2T) {
  __shared__ float t[32][33];
  const int z = blockIdx.z;
  const float* sp; unsigned short* dp;
  if (z < 8) {
    sp = ((z < 4) ? sw1 : rw1) + (size_t)(z & 3) * 832 * DD;
    dp = w1T + (size_t)z * DD * DD;
  } else {
    int zz = z - 8;
    sp = ((zz < 4) ? sw2 : rw2) + (size_t)(zz & 3) * DD * DD;
    dp = w2T + (size_t)zz * DD * DD;
  }
  const int r0 = blockIdx.x * 32, c0 = blockIdx.y * 32;
  const int tx = threadIdx.x & 31, ty = threadIdx.x >> 5;
#pragma unroll
  for (int i = 0; i < 4; i++) {
    int r = ty + i * 8;
    t[r][tx] = sp[(size_t)(r0 + r) * DD + c0 + tx];
  }
  __syncthreads();
#pragma unroll
  for (int i = 0; i < 4; i++) {
    int cc = ty + i * 8;
    dp[(size_t)(c0 + cc) * DD + r0 + tx] = f2bf(t[tx][cc]);
  }
}

// ---------------------------------------------------------------- col mean
__global__ void colmean1(const float* __restrict__ geo, float* __restrict__ gp) {
  const int b = blockIdx.z, yc = blockIdx.y;
  const int col = blockIdx.x * 256 + threadIdx.x;
  const float* p = geo + (size_t)b * 1024 * DD + (size_t)yc * 128 * DD + col;
  float s = 0.f;
  for (int n = 0; n < 128; ++n) s += p[(size_t)n * DD];
  gp[((size_t)b * 8 + yc) * DD + col] = s;
}
__global__ void colmean2(const float* __restrict__ gp, float* __restrict__ gm) {
  const int b = blockIdx.y;
  const int col = blockIdx.x * 256 + threadIdx.x;
  float s = 0.f;
#pragma unroll
  for (int i = 0; i < 8; ++i) s += gp[((size_t)b * 8 + i) * DD + col];
  gm[(size_t)b * DD + col] = s * (1.0f / 1024.0f);
}

// ---------------------------------------------------------------- tiny MLPs
static __device__ float2 blk_sum2(float a, float b, float* red) {
  const int tid = threadIdx.x;   // blockDim == 384
  __syncthreads();
  red[tid] = a; red[512 + tid] = b;
  if (tid < 128) { red[384 + tid] = 0.f; red[512 + 384 + tid] = 0.f; }
  __syncthreads();
  for (int s = 256; s > 0; s >>= 1) {
    if (tid < s) { red[tid] += red[tid + s]; red[512 + tid] += red[512 + tid + s]; }
    __syncthreads();
  }
  return make_float2(red[0], red[512]);
}

__global__ void small_mlp(
    const float* __restrict__ gc_mean, const float* __restrict__ qf,
    const int* __restrict__ mask,
    const float* __restrict__ gp_w1, const float* __restrict__ gp_b1,
    const float* __restrict__ gp_g1, const float* __restrict__ gp_be1,
    const float* __restrict__ gp_w2, const float* __restrict__ gp_b2,
    const float* __restrict__ swp_w1, const float* __restrict__ swp_b1,
    const float* __restrict__ swp_g1, const float* __restrict__ swp_be1,
    const float* __restrict__ swp_w2, const float* __restrict__ swp_b2,
    const float* __restrict__ swp_g2, const float* __restrict__ swp_be2,
    const float* __restrict__ swp_w3, const float* __restrict__ swp_b3,
    float* __restrict__ cxfs, float* __restrict__ cxfu,
    float* __restrict__ aw)
{
  __shared__ float gm[768];
  __shared__ float buf[832];
  __shared__ float tmp[384];
  __shared__ float red[1024];
  const int b = blockIdx.x, tid = threadIdx.x;

  for (int i = tid; i < 768; i += 384) gm[i] = gc_mean[b * 768 + i];
  __syncthreads();

  float z = gp_b1[tid];
  for (int k = 0; k < 768; k++) z += gm[k] * gp_w1[k * 384 + tid];
  float2 s = blk_sum2(z, z * z, red);
  {
    float mean = s.x * (1.f / 384.f);
    float rinv = rsqrtf(s.y * (1.f / 384.f) - mean * mean + 1e-5f);
    float y = (z - mean) * rinv * gp_g1[tid] + gp_be1[tid];
    tmp[tid] = fmaxf(y, 0.f);
  }
  __syncthreads();

  if (tid < 64) {
    float g = gp_b2[tid];
    for (int k = 0; k < 384; k++) g += tmp[k] * gp_w2[k * 64 + tid];
    float sc = (mask[b] != 0) ? 1.0f : 0.1f;
    cxfs[b * 64 + tid] = g * sc;
    cxfu[b * 64 + tid] = g;
    buf[tid] = g;
  }
  for (int i = tid; i < 768; i += 384) buf[64 + i] = qf[b * 768 + i];
  __syncthreads();

  float z1 = 0.f;
  if (tid < 256) {
    z1 = swp_b1[tid];
    for (int k = 0; k < 832; k++) z1 += buf[k] * swp_w1[k * 256 + tid];
  }
  s = blk_sum2(z1, z1 * z1, red);
  {
    float mean = s.x * (1.f / 256.f);
    float rinv = rsqrtf(s.y * (1.f / 256.f) - mean * mean + 1e-5f);
    if (tid < 256) {
      float y = (z1 - mean) * rinv * swp_g1[tid] + swp_be1[tid];
      tmp[tid] = 0.5f * y * (1.f + erff(y * 0.7071067811865476f));
    }
  }
  __syncthreads();

  float z2 = 0.f;
  if (tid < 128) {
    z2 = swp_b2[tid];
    for (int k = 0; k < 256; k++) z2 += tmp[k] * swp_w2[k * 128 + tid];
  }
  s = blk_sum2(z2, z2 * z2, red);
  {
    float mean = s.x * (1.f / 128.f);
    float rinv = rsqrtf(s.y * (1.f / 128.f) - mean * mean + 1e-5f);
    if (tid < 128) {
      float y = (z2 - mean) * rinv * swp_g2[tid] + swp_be2[tid];
      tmp[tid] = 0.5f * y * (1.f + erff(y * 0.7071067811865476f));
    }
  }
  __syncthreads();

  if (tid < 8) {
    float z3 = swp_b3[tid];
    for (int k = 0; k < 128; k++) z3 += tmp[k] * swp_w3[k * 8 + tid];
    buf[tid] = z3;
  }
  __syncthreads();
  if (tid < 8) {
    float mx = buf[0];
    for (int k = 1; k < 8; k++) mx = fmaxf(mx, buf[k]);
    float ssum = 0.f;
    for (int k = 0; k < 8; k++) ssum += expf(buf[k] - mx);
    aw[b * 8 + tid] = expf(buf[tid] - mx) / ssum;
  }
}

// ---------------------------------------------------------------- ctx->bias
__global__ void ctxbias_k(const float* __restrict__ cxfs,
                          const float* __restrict__ cxfu,
                          const float* __restrict__ sw1, const float* __restrict__ rw1,
                          const float* __restrict__ sb1, const float* __restrict__ rb1,
                          float* __restrict__ b1x)
{
  const int br = blockIdx.x, b = blockIdx.y, tid = threadIdx.x;
  __shared__ float cf[64];
  if (tid < 64) cf[tid] = ((br <= 4) ? cxfs : cxfu)[b * 64 + tid];
  __syncthreads();
  const float* W = ((br < 4) ? sw1 + (size_t)br * 832 * DD
                             : rw1 + (size_t)(br - 4) * 832 * DD) + (size_t)768 * DD;
  const float* bb = (br < 4) ? sb1 + br * DD : rb1 + (br - 4) * DD;
#pragma unroll
  for (int jj = 0; jj < 3; ++jj) {
    const int f = tid + jj * 256;
    float s = bb[f];
    for (int k = 0; k < 64; ++k) s += cf[k] * W[(size_t)k * DD + f];
    b1x[((size_t)br * 16 + b) * DD + f] = s;
  }
}

// ---------------------------------------------------------------- stats
__global__ void stats_k(const float2* __restrict__ part, float2* __restrict__ st,
                        int nr) {
  int i = blockIdx.x * 256 + threadIdx.x;
  if (i >= nr) return;
  float s1 = 0.f, s2 = 0.f;
#pragma unroll
  for (int s = 0; s < 3; ++s) {
    float2 p = part[(size_t)s * nr + i];
    s1 += p.x; s2 += p.y;
  }
  float mean = s1 * (1.f / 768.f);
  float var = s2 * (1.f / 768.f) - mean * mean;
  float rinv = rsqrtf(var + 1e-5f);
  st[i] = make_float2(rinv, -mean * rinv);
}

// ================================================================ GEMM1
// R11 structure; grid remap: nt INNERMOST per XCD stream so the 3 nt-blocks
// sharing one A-panel are co-resident on the same XCD (L2-hot A).
__global__ __launch_bounds__(512, 4)
void gemm1_k(const float* __restrict__ comps,
             const unsigned short* __restrict__ w1T,
             const float* __restrict__ b1x,
             unsigned short* __restrict__ z1,
             float2* __restrict__ part1,
             const int* __restrict__ mask)
{
  __shared__ __align__(16) unsigned short As[2][4096];
  __shared__ __align__(16) unsigned short Bs[2][8192];
  __shared__ float pscr[4][128][2];
  constexpr int NT = 24;

  const int id = blockIdx.x;
  const int x = id & 7, j = id >> 3;        // j 0..383 per-XCD stream
  const int nt = j % 3;                     // innermost: A-panel reuse
  const int r2 = j / 3;                     // 0..127
  const int br = r2 >> 4;                   // 0..7
  const int mt = ((r2 & 15) << 3) | x;      // 0..127
  const int m0 = mt * 128, n0 = nt * 256;
  const int b = m0 >> 10;
  if (br >= 5 && mask[b] == 0) return;

  const int ci = (0x76245310u >> (br * 4)) & 15;
  const float* afp = comps + (size_t)ci * MT * DD + (size_t)m0 * DD;
  const unsigned short* wT = w1T + (size_t)br * DD * DD + (size_t)n0 * DD;

  const int tid = threadIdx.x;
  const int w = tid >> 6, lane = tid & 63, llo = lane & 15, lhi = lane >> 4;
  const int wm = w & 1, wn = w >> 1;

  // A staging: 1 slot (16B) per thread; write-side swizzle
  const int arow = tid >> 2, ap = tid & 3;
  const int aslot = (arow * 32 + ((ap ^ ((arow >> 1) & 3)) << 3));
  const float* asrc = afp + (size_t)arow * DD + ap * 8;

  // B staging: 2 DMAs per wave, pre-swizzled source
  const int q = lane & 3, rrB = w * 16 + (lane >> 2);
  const int swqB = q ^ ((rrB >> 1) & 3);
  const unsigned short* bsrc0 = wT + (size_t)rrB * DD + swqB * 8;
  const unsigned short* bsrc1 = wT + (size_t)(128 + rrB) * DD + swqB * 8;

  f32x4 acc[4][4];
#pragma unroll
  for (int mf = 0; mf < 4; ++mf)
#pragma unroll
    for (int nf = 0; nf < 4; ++nf) acc[mf][nf] = (f32x4)0.0f;

  struct St { u32x4 q0, q1; };

  auto issueB = [&](int kt, int s) {
    gload_lds16(bsrc0 + (size_t)kt * 32, &Bs[s][w * 512]);
    gload_lds16(bsrc1 + (size_t)kt * 32, &Bs[s][4096 + w * 512]);
  };
  auto loadA = [&](int kt) -> St {
    St s;
    const u32x4* p = (const u32x4*)(asrc + kt * 32);
    s.q0 = p[0]; s.q1 = p[1];
    return s;
  };
  auto commitA = [&](const St& s, int sl) {
    u32x4 v;
    v[0] = pk2(__uint_as_float(s.q0[0]), __uint_as_float(s.q0[1]));
    v[1] = pk2(__uint_as_float(s.q0[2]), __uint_as_float(s.q0[3]));
    v[2] = pk2(__uint_as_float(s.q1[0]), __uint_as_float(s.q1[1]));
    v[3] = pk2(__uint_as_float(s.q1[2]), __uint_as_float(s.q1[3]));
    *(u32x4*)&As[sl][aslot] = v;
  };

  const int aswz = (lhi ^ ((llo >> 1) & 3)) << 3;
  const int arow0 = (wm * 64 + llo) * 32 + aswz;
  const int brow0 = (wn * 64 + llo) * 32 + aswz;
  auto compute = [&](int sl) {
    short8 afr[4];
#pragma unroll
    for (int mf = 0; mf < 4; ++mf)
      afr[mf] = *(const short8*)&As[sl][arow0 + mf * 512];
#pragma unroll
    for (int nf = 0; nf < 4; ++nf) {
      short8 bfr = *(const short8*)&Bs[sl][brow0 + nf * 512];
#pragma unroll
      for (int mf = 0; mf < 4; ++mf)
        acc[mf][nf] = __builtin_amdgcn_mfma_f32_16x16x32_bf16(afr[mf], bfr, acc[mf][nf], 0, 0, 0);
    }
  };

  // prologue
  issueB(0, 0);
  {
    St s0 = loadA(0);
    commitA(s0, 0);
  }
  asm volatile("s_waitcnt lgkmcnt(0)" ::: "memory");
  __builtin_amdgcn_sched_barrier(0);
  __builtin_amdgcn_s_barrier();

#pragma unroll 1
  for (int t = 0; t < NT; ++t) {
    const int cur = t & 1, nxt = cur ^ 1;
    const bool more = (t + 1 < NT);
    St sn;
    if (more) {
      issueB(t + 1, nxt);               // DMA in flight under MFMA
      sn = loadA(t + 1);                // global->reg, lands under MFMA
    }
    __builtin_amdgcn_sched_barrier(0);  // pin issues before compute
    compute(cur);
    __builtin_amdgcn_sched_barrier(0);  // pin commit after compute (T14)
    if (more) commitA(sn, nxt);         // auto-vmcnt: also retires B(t+1)
    asm volatile("s_waitcnt lgkmcnt(0)" ::: "memory");
    __builtin_amdgcn_sched_barrier(0);
    __builtin_amdgcn_s_barrier();
  }

  // epilogue: bias(b1x), z-store bf16, row partials
  const float* bias = b1x + ((size_t)br * 16 + b) * DD;
  unsigned short* zo = z1 + (size_t)br * MT * DD + (size_t)m0 * DD;
  const int n0w = n0 + wn * 64;
  float bia[4];
#pragma unroll
  for (int nf = 0; nf < 4; ++nf) bia[nf] = bias[n0w + nf * 16 + llo];
#pragma unroll
  for (int mf = 0; mf < 4; ++mf) {
#pragma unroll
    for (int r = 0; r < 4; ++r) {
      float zz[4]; float s1v = 0.f, s2v = 0.f;
#pragma unroll
      for (int nf = 0; nf < 4; ++nf) {
        float zv = acc[mf][nf][r] + bia[nf];
        zz[nf] = zv; s1v += zv; s2v += zv * zv;
      }
      const int rloc = wm * 64 + mf * 16 + lhi * 4 + r;
      const size_t rowoff = (size_t)rloc * DD;
#pragma unroll
      for (int nf = 0; nf < 4; ++nf) {
        float zon = __shfl_xor(zz[nf], 1);
        if ((llo & 1) == 0)
          *(unsigned*)&zo[rowoff + n0w + nf * 16 + llo] = pk2(zz[nf], zon);
      }
#pragma unroll
      for (int d = 1; d < 16; d <<= 1) {
        s1v += __shfl_xor(s1v, d); s2v += __shfl_xor(s2v, d);
      }
      if (llo == 0) { pscr[wn][rloc][0] = s1v; pscr[wn][rloc][1] = s2v; }
    }
  }
  __syncthreads();
  if (tid < 128) {
    float a = 0.f, c = 0.f;
#pragma unroll
    for (int qq = 0; qq < 4; ++qq) { a += pscr[qq][tid][0]; c += pscr[qq][tid][1]; }
    part1[(size_t)nt * (8 * MT) + (size_t)br * MT + m0 + tid] = make_float2(a, c);
  }
}

// ---------------------------------------------------------------- act1
__global__ void act1_k(const unsigned short* __restrict__ z1,
                       const float2* __restrict__ st1,
                       const float* __restrict__ sg1, const float* __restrict__ sbe1,
                       const float* __restrict__ rg1, const float* __restrict__ rbe1,
                       const int* __restrict__ mask,
                       unsigned short* __restrict__ a1)
{
  const int tid = threadIdx.x;
  const int rowg = blockIdx.x * 8 + (tid >> 5);   // 0..131071
  const int l = tid & 31;
  const int br = rowg >> 14;
  const int r = rowg & 16383;
  const int b = r >> 10;
  if (br >= 5 && mask[b] == 0) return;
  const bool isg = (br < 4);
  const float* g  = (isg ? sg1  + br * DD : rg1  + (br - 4) * DD);
  const float* be = (isg ? sbe1 + br * DD : rbe1 + (br - 4) * DD);
  const float2 stv = st1[rowg];
  const unsigned short* zp = z1 + (size_t)rowg * DD;
  unsigned short* op = a1 + (size_t)rowg * DD;
#pragma unroll
  for (int c = 0; c < 3; ++c) {
    const int col = l * 8 + c * 256;
    u32x4 zv = *(const u32x4*)(zp + col);
    fv4 ga = *(const fv4*)(g + col), gb = *(const fv4*)(g + col + 4);
    fv4 ba = *(const fv4*)(be + col), bb = *(const fv4*)(be + col + 4);
    float y[8];
#pragma unroll
    for (int wd = 0; wd < 2; ++wd) {
      y[2*wd]   = fmaf(fmaf(bf2f((unsigned short)(zv[wd] & 0xffffu)), stv.x, stv.y), ga[2*wd], ba[2*wd]);
      y[2*wd+1] = fmaf(fmaf(bf2f((unsigned short)(zv[wd] >> 16)), stv.x, stv.y), ga[2*wd+1], ba[2*wd+1]);
      y[4+2*wd]   = fmaf(fmaf(bf2f((unsigned short)(zv[wd+2] & 0xffffu)), stv.x, stv.y), gb[2*wd], bb[2*wd]);
      y[4+2*wd+1] = fmaf(fmaf(bf2f((unsigned short)(zv[wd+2] >> 16)), stv.x, stv.y), gb[2*wd+1], bb[2*wd+1]);
    }
    u32x4 ov;
#pragma unroll
    for (int wd = 0; wd < 4; ++wd) {
      float y0 = y[2*wd], y1 = y[2*wd+1];
      if (isg) { y0 = gelu_t(y0); y1 = gelu_t(y1); }
      else     { y0 = fmaxf(y0, 0.f); y1 = fmaxf(y1, 0.f); }
      ov[wd] = pk2(y0, y1);
    }
    *(u32x4*)(op + col) = ov;
  }
}

// ================================================================ GEMM2
// R11 structure; same nt-innermost remap for a1-panel L2 reuse.
__global__ __launch_bounds__(512, 4)
void gemm2_k(const float* __restrict__ comps,
             const unsigned short* __restrict__ a1,
             const unsigned short* __restrict__ w2T,
             const float* __restrict__ sb2, const float* __restrict__ rb2,
             unsigned short* __restrict__ z2,
             float2* __restrict__ part2,
             float* __restrict__ outp,
             const int* __restrict__ mask)
{
  __shared__ __align__(16) unsigned short As[3][4096];
  __shared__ __align__(16) unsigned short Bs[3][8192];
  __shared__ float pscr[4][128][2];
  constexpr int NT = 24;

  const int id = blockIdx.x;
  const int x = id & 7, j = id >> 3;
  const int nt = j % 3;
  const int r2 = j / 3;
  const int br = r2 >> 4;
  const int mt = ((r2 & 15) << 3) | x;
  const int m0 = mt * 128, n0 = nt * 256;
  const int b = m0 >> 10;
  const int ci = (0x76245310u >> (br * 4)) & 15;
  const int tid = threadIdx.x;

  if (br >= 5 && mask[b] == 0) {            // masked: out = comps tile
    const float* cs = comps + (size_t)ci * MT * DD + (size_t)m0 * DD + n0;
    float* cd = outp + (size_t)ci * MT * DD + (size_t)m0 * DD + n0;
#pragma unroll 1
    for (int k = 0; k < 16; ++k) {
      int idx = tid + k * 512;
      int r3 = idx >> 6, c4 = (idx & 63) * 4;
      *(fv4*)(cd + (size_t)r3 * DD + c4) = *(const fv4*)(cs + (size_t)r3 * DD + c4);
    }
    return;
  }

  const unsigned short* az = a1 + (size_t)br * MT * DD + (size_t)m0 * DD;
  const unsigned short* wT = w2T + (size_t)br * DD * DD + (size_t)n0 * DD;

  const int w = tid >> 6, lane = tid & 63, llo = lane & 15, lhi = lane >> 4;
  const int wm = w & 1, wn = w >> 1;
  const int q = lane & 3, rrB = w * 16 + (lane >> 2);
  const int swqB = q ^ ((rrB >> 1) & 3);

  const unsigned short* asrcD = az + (size_t)rrB * DD + swqB * 8;
  const unsigned short* bsrc0 = wT + (size_t)rrB * DD + swqB * 8;
  const unsigned short* bsrc1 = wT + (size_t)(128 + rrB) * DD + swqB * 8;

  f32x4 acc[4][4];
#pragma unroll
  for (int mf = 0; mf < 4; ++mf)
#pragma unroll
    for (int nf = 0; nf < 4; ++nf) acc[mf][nf] = (f32x4)0.0f;

  auto issueT = [&](int kt, int s) {        // 3 DMAs per thread per tile
    gload_lds16(asrcD + (size_t)kt * 32, &As[s][w * 512]);
    gload_lds16(bsrc0 + (size_t)kt * 32, &Bs[s][w * 512]);
    gload_lds16(bsrc1 + (size_t)kt * 32, &Bs[s][4096 + w * 512]);
  };

  const int aswz = (lhi ^ ((llo >> 1) & 3)) << 3;
  const int arow0 = (wm * 64 + llo) * 32 + aswz;
  const int brow0 = (wn * 64 + llo) * 32 + aswz;
  auto compute = [&](int sl) {
    short8 afr[4];
#pragma unroll
    for (int mf = 0; mf < 4; ++mf)
      afr[mf] = *(const short8*)&As[sl][arow0 + mf * 512];
#pragma unroll
    for (int nf = 0; nf < 4; ++nf) {
      short8 bfr = *(const short8*)&Bs[sl][brow0 + nf * 512];
#pragma unroll
      for (int mf = 0; mf < 4; ++mf)
        acc[mf][nf] = __builtin_amdgcn_mfma_f32_16x16x32_bf16(afr[mf], bfr, acc[mf][nf], 0, 0, 0);
    }
  };

  // prologue: tiles 0,1 in flight; wait tile 0 only
  issueT(0, 0);
  issueT(1, 1);
  asm volatile("s_waitcnt vmcnt(3)" ::: "memory");
  __builtin_amdgcn_sched_barrier(0);
  __builtin_amdgcn_s_barrier();

  int sc = 0;
#pragma unroll 1
  for (int t = 0; t < NT; ++t) {
    int s2 = sc + 2; if (s2 >= 3) s2 -= 3;
    const bool more = (t + 2 < NT);
    if (more) issueT(t + 2, s2);
    __builtin_amdgcn_sched_barrier(0);
    compute(sc);
    if (more) asm volatile("s_waitcnt vmcnt(3)" ::: "memory");
    else      asm volatile("s_waitcnt vmcnt(0)" ::: "memory");
    asm volatile("s_waitcnt lgkmcnt(0)" ::: "memory");
    __builtin_amdgcn_sched_barrier(0);
    __builtin_amdgcn_s_barrier();
    ++sc; if (sc == 3) sc = 0;
  }

  // epilogue
  const int n0w = n0 + wn * 64;
  const float* bias = ((br < 4) ? sb2 : rb2) + (br & 3) * DD;
  float bia[4];
#pragma unroll
  for (int nf = 0; nf < 4; ++nf) bia[nf] = bias[n0w + nf * 16 + llo];

  if (br < 4) {
    unsigned short* zo = z2 + (size_t)br * MT * DD + (size_t)m0 * DD;
#pragma unroll
    for (int mf = 0; mf < 4; ++mf) {
#pragma unroll
      for (int r = 0; r < 4; ++r) {
        float zz[4]; float s1v = 0.f, s2v = 0.f;
#pragma unroll
        for (int nf = 0; nf < 4; ++nf) {
          float zv = acc[mf][nf][r] + bia[nf];
          zz[nf] = zv; s1v += zv; s2v += zv * zv;
        }
        const int rloc = wm * 64 + mf * 16 + lhi * 4 + r;
        const size_t rowoff = (size_t)rloc * DD;
#pragma unroll
        for (int nf = 0; nf < 4; ++nf) {
          float zon = __shfl_xor(zz[nf], 1);
          if ((llo & 1) == 0)
            *(unsigned*)&zo[rowoff + n0w + nf * 16 + llo] = pk2(zz[nf], zon);
        }
#pragma unroll
        for (int d = 1; d < 16; d <<= 1) {
          s1v += __shfl_xor(s1v, d); s2v += __shfl_xor(s2v, d);
        }
        if (llo == 0) { pscr[wn][rloc][0] = s1v; pscr[wn][rloc][1] = s2v; }
      }
    }
    __syncthreads();
    if (tid < 128) {
      float a = 0.f, c = 0.f;
#pragma unroll
      for (int qq = 0; qq < 4; ++qq) { a += pscr[qq][tid][0]; c += pscr[qq][tid][1]; }
      part2[(size_t)nt * (4 * MT) + (size_t)br * MT + m0 + tid] = make_float2(a, c);
    }
  } else {
    float* fo = outp + (size_t)ci * MT * DD + (size_t)m0 * DD;
#pragma unroll
    for (int mf = 0; mf < 4; ++mf) {
#pragma unroll
      for (int r = 0; r < 4; ++r) {
        const int rloc = wm * 64 + mf * 16 + lhi * 4 + r;
        const size_t rowoff = (size_t)rloc * DD;
#pragma unroll
        for (int nf = 0; nf < 4; ++nf)
          fo[rowoff + n0w + nf * 16 + llo] = acc[mf][nf][r] + bia[nf];
      }
    }
  }
}

// ---------------------------------------------------------------- finish s
__global__ void finish_s(const unsigned short* __restrict__ z2,
                         const float2* __restrict__ st2,
                         const float* __restrict__ sg2,
                         const float* __restrict__ sbe2,
                         float* __restrict__ outp)
{
  const int tid = threadIdx.x;
  const int rowg = blockIdx.x * 8 + (tid >> 5);     // 0..65535
  const int l = tid & 31;
  const int br = rowg >> 14;
  const int r = rowg & 16383;
  const int ci = (0x5310u >> (br * 4)) & 15;
  const unsigned short* zp = z2 + (size_t)rowg * DD;
  float* op = outp + (size_t)ci * MT * DD + (size_t)r * DD;
  const float2 stv = st2[rowg];
  const float* g = sg2 + br * DD;
  const float* be = sbe2 + br * DD;
#pragma unroll
  for (int c = 0; c < 3; ++c) {
    const int col = l * 8 + c * 256;
    u32x4 zv = *(const u32x4*)(zp + col);
    fv4 ga = *(const fv4*)(g + col), gb = *(const fv4*)(g + col + 4);
    fv4 ba = *(const fv4*)(be + col), bb = *(const fv4*)(be + col + 4);
    fv4 o0, o1;
#pragma unroll
    for (int wd = 0; wd < 2; ++wd) {
      o0[2 * wd]     = fmaf(fmaf(bf2f((unsigned short)(zv[wd] & 0xffffu)), stv.x, stv.y), ga[2 * wd], ba[2 * wd]);
      o0[2 * wd + 1] = fmaf(fmaf(bf2f((unsigned short)(zv[wd] >> 16)), stv.x, stv.y), ga[2 * wd + 1], ba[2 * wd + 1]);
      o1[2 * wd]     = fmaf(fmaf(bf2f((unsigned short)(zv[wd + 2] & 0xffffu)), stv.x, stv.y), gb[2 * wd], bb[2 * wd]);
      o1[2 * wd + 1] = fmaf(fmaf(bf2f((unsigned short)(zv[wd + 2] >> 16)), stv.x, stv.y), gb[2 * wd + 1], bb[2 * wd + 1]);
    }
    *(fv4*)(op + col) = o0;
    *(fv4*)(op + col + 4) = o1;
  }
}

// ---------------------------------------------------------------- launch
extern "C" void kernel_launch(void* const* d_in, const int* in_sizes, int n_in,
                              void* d_out, int out_size, void* d_ws, size_t ws_size,
                              hipStream_t stream)
{
  (void)in_sizes; (void)n_in; (void)out_size; (void)ws_size;
  const float* comps  = (const float*)d_in[0];
  const float* geo    = (const float*)d_in[1];
  const float* qf     = (const float*)d_in[2];
  const int*   mask   = (const int*)d_in[3];
  const float* gp_w1  = (const float*)d_in[4];
  const float* gp_b1  = (const float*)d_in[5];
  const float* gp_g1  = (const float*)d_in[6];
  const float* gp_be1 = (const float*)d_in[7];
  const float* gp_w2  = (const float*)d_in[8];
  const float* gp_b2  = (const float*)d_in[9];
  const float* swp_w1 = (const float*)d_in[10];
  const float* swp_b1 = (const float*)d_in[11];
  const float* swp_g1 = (const float*)d_in[12];
  const float* swp_be1= (const float*)d_in[13];
  const float* swp_w2 = (const float*)d_in[14];
  const float* swp_b2 = (const float*)d_in[15];
  const float* swp_g2 = (const float*)d_in[16];
  const float* swp_be2= (const float*)d_in[17];
  const float* swp_w3 = (const float*)d_in[18];
  const float* swp_b3 = (const float*)d_in[19];
  const float* sw1 = (const float*)d_in[20];
  const float* sb1 = (const float*)d_in[21];
  const float* sg1 = (const float*)d_in[22];
  const float* sbe1= (const float*)d_in[23];
  const float* sw2 = (const float*)d_in[24];
  const float* sb2 = (const float*)d_in[25];
  const float* sg2 = (const float*)d_in[26];
  const float* sbe2= (const float*)d_in[27];
  const float* rw1 = (const float*)d_in[28];
  const float* rb1 = (const float*)d_in[29];
  const float* rg1 = (const float*)d_in[30];
  const float* rbe1= (const float*)d_in[31];
  const float* rw2 = (const float*)d_in[32];
  const float* rb2 = (const float*)d_in[33];
  float* out = (float*)d_out;

  char* ws = (char*)d_ws;
  unsigned short* w1T = (unsigned short*)(ws + OFF_W1T);
  unsigned short* w2T = (unsigned short*)(ws + OFF_W2T);
  unsigned short* z1  = (unsigned short*)(ws + OFF_Z1);
  unsigned short* z2  = (unsigned short*)(ws + OFF_Z2);
  float2* part1 = (float2*)(ws + OFF_P1);
  float2* part2 = (float2*)(ws + OFF_P2);
  float2* st1   = (float2*)(ws + OFF_ST1);
  float2* st2   = (float2*)(ws + OFF_ST2);
  float* gpart  = (float*)(ws + OFF_GP);
  float* gmean  = (float*)(ws + OFF_GM);
  float* cxfs   = (float*)(ws + OFF_CXF);
  float* cxfu   = (float*)(ws + OFF_CXF + 4096);
  float* b1x    = (float*)(ws + OFF_B1X);
  unsigned short* a1 = (unsigned short*)(ws + OFF_A1);

  transpose_cvt<<<dim3(24, 24, 16), 256, 0, stream>>>(sw1, rw1, sw2, rw2, w1T, w2T);
  colmean1<<<dim3(3, 8, 16), 256, 0, stream>>>(geo, gpart);
  colmean2<<<dim3(3, 16), 256, 0, stream>>>(gpart, gmean);
  small_mlp<<<16, 384, 0, stream>>>(gmean, qf, mask,
      gp_w1, gp_b1, gp_g1, gp_be1, gp_w2, gp_b2,
      swp_w1, swp_b1, swp_g1, swp_be1, swp_w2, swp_b2, swp_g2, swp_be2,
      swp_w3, swp_b3, cxfs, cxfu, out + AW_OFF);
  ctxbias_k<<<dim3(8, 16), 256, 0, stream>>>(cxfs, cxfu, sw1, rw1, sb1, rb1, b1x);

  gemm1_k<<<3072, 512, 0, stream>>>(comps, w1T, b1x, z1, part1, mask);
  stats_k<<<512, 256, 0, stream>>>(part1, st1, 8 * MT);
  act1_k<<<16384, 256, 0, stream>>>(z1, st1, sg1, sbe1, rg1, rbe1, mask, a1);
  gemm2_k<<<3072, 512, 0, stream>>>(comps, a1, w2T, sb2, rb2, z2, part2, out, mask);
  stats_k<<<256, 256, 0, stream>>>(part2, st2, 4 * MT);
  finish_s<<<8192, 256, 0, stream>>>(z2, st2, sg2, sbe2, out);
}

// Round 13
// 779.192 us; speedup vs baseline: 1.0227x; 1.0227x over previous
//
#include <hip/hip_runtime.h>
#include <math.h>

#define MT 16384          // B*N rows
#define DD 768
#define AW_OFF ((size_t)8 * MT * DD)

typedef __attribute__((ext_vector_type(8))) short short8;
typedef __attribute__((ext_vector_type(4))) float f32x4;
typedef __attribute__((ext_vector_type(4))) float fv4;
typedef __attribute__((ext_vector_type(4))) unsigned int u32x4;

// ---- workspace offsets (bytes) ----
#define OFF_W1T 0ULL                    // 8*768*768*2 = 9,437,184
#define OFF_W2T 9437184ULL              // 8*768*768*2 = 9,437,184
#define OFF_Z1  19660800ULL             // 8*MT*768*2  = 201,326,592
#define OFF_Z2  220987392ULL            // 4*MT*768*2  = 100,663,296
#define OFF_P1  321650688ULL            // 3*131072*8  = 3,145,728
#define OFF_P2  327942144ULL            // 3*65536*8   = 1,572,864
#define OFF_ST1 331087872ULL            // 131072*8    = 1,048,576
#define OFF_ST2 332136448ULL            // 65536*8     = 524,288
#define OFF_GP  332660736ULL            // 16*8*768*4  = 393,216
#define OFF_GM  333053952ULL            // 16*768*4    = 49,152
#define OFF_CXF 333103104ULL            // 2*16*64*4   = 8,192
#define OFF_B1X 333111296ULL            // 8*16*768*4  = 393,216
#define OFF_A1  335544320ULL            // 8*MT*768*2  = 201,326,592 (ends 512MB)

static __device__ __forceinline__ unsigned short f2bf(float f) {
  unsigned u = __float_as_uint(f);
  u += 0x7fffu + ((u >> 16) & 1u);
  return (unsigned short)(u >> 16);
}
static __device__ __forceinline__ float bf2f(unsigned short h) {
  return __uint_as_float(((unsigned)h) << 16);
}
static __device__ __forceinline__ unsigned pk2(float lo, float hi) {
  return (unsigned)f2bf(lo) | ((unsigned)f2bf(hi) << 16);
}
static __device__ __forceinline__ float gelu_t(float y) {
  float y2 = y * y;
  float c = fmaf(y2, 0.0713548163f, 1.59576912161f);
  float e = __expf(-y * c);
  return y / (1.0f + e);
}
static __device__ __forceinline__ void gload_lds16(const void* g, void* l) {
  __builtin_amdgcn_global_load_lds(
      (const __attribute__((address_space(1))) void*)g,
      (__attribute__((address_space(3))) void*)l, 16, 0, 0);
}

// ---------------------------------------------------------------- transpose
__global__ void transpose_cvt(const float* sw1, const float* rw1,
                              const float* sw2, const float* rw2,
                              unsigned short* w1T, unsigned short* w2T) {
  __shared__ float t[32][33];
  const int z = blockIdx.z;
  const float* sp; unsigned short* dp;
  if (z < 8) {
    sp = ((z < 4) ? sw1 : rw1) + (size_t)(z & 3) * 832 * DD;
    dp = w1T + (size_t)z * DD * DD;
  } else {
    int zz = z - 8;
    sp = ((zz < 4) ? sw2 : rw2) + (size_t)(zz & 3) * DD * DD;
    dp = w2T + (size_t)zz * DD * DD;
  }
  const int r0 = blockIdx.x * 32, c0 = blockIdx.y * 32;
  const int tx = threadIdx.x & 31, ty = threadIdx.x >> 5;
#pragma unroll
  for (int i = 0; i < 4; i++) {
    int r = ty + i * 8;
    t[r][tx] = sp[(size_t)(r0 + r) * DD + c0 + tx];
  }
  __syncthreads();
#pragma unroll
  for (int i = 0; i < 4; i++) {
    int cc = ty + i * 8;
    dp[(size_t)(c0 + cc) * DD + r0 + tx] = f2bf(t[tx][cc]);
  }
}

// ---------------------------------------------------------------- col mean
__global__ void colmean1(const float* __restrict__ geo, float* __restrict__ gp) {
  const int b = blockIdx.z, yc = blockIdx.y;
  const int col = blockIdx.x * 256 + threadIdx.x;
  const float* p = geo + (size_t)b * 1024 * DD + (size_t)yc * 128 * DD + col;
  float s = 0.f;
  for (int n = 0; n < 128; ++n) s += p[(size_t)n * DD];
  gp[((size_t)b * 8 + yc) * DD + col] = s;
}
__global__ void colmean2(const float* __restrict__ gp, float* __restrict__ gm) {
  const int b = blockIdx.y;
  const int col = blockIdx.x * 256 + threadIdx.x;
  float s = 0.f;
#pragma unroll
  for (int i = 0; i < 8; ++i) s += gp[((size_t)b * 8 + i) * DD + col];
  gm[(size_t)b * DD + col] = s * (1.0f / 1024.0f);
}

// ---------------------------------------------------------------- tiny MLPs
static __device__ float2 blk_sum2(float a, float b, float* red) {
  const int tid = threadIdx.x;   // blockDim == 384
  __syncthreads();
  red[tid] = a; red[512 + tid] = b;
  if (tid < 128) { red[384 + tid] = 0.f; red[512 + 384 + tid] = 0.f; }
  __syncthreads();
  for (int s = 256; s > 0; s >>= 1) {
    if (tid < s) { red[tid] += red[tid + s]; red[512 + tid] += red[512 + tid + s]; }
    __syncthreads();
  }
  return make_float2(red[0], red[512]);
}

__global__ void small_mlp(
    const float* __restrict__ gc_mean, const float* __restrict__ qf,
    const int* __restrict__ mask,
    const float* __restrict__ gp_w1, const float* __restrict__ gp_b1,
    const float* __restrict__ gp_g1, const float* __restrict__ gp_be1,
    const float* __restrict__ gp_w2, const float* __restrict__ gp_b2,
    const float* __restrict__ swp_w1, const float* __restrict__ swp_b1,
    const float* __restrict__ swp_g1, const float* __restrict__ swp_be1,
    const float* __restrict__ swp_w2, const float* __restrict__ swp_b2,
    const float* __restrict__ swp_g2, const float* __restrict__ swp_be2,
    const float* __restrict__ swp_w3, const float* __restrict__ swp_b3,
    float* __restrict__ cxfs, float* __restrict__ cxfu,
    float* __restrict__ aw)
{
  __shared__ float gm[768];
  __shared__ float buf[832];
  __shared__ float tmp[384];
  __shared__ float red[1024];
  const int b = blockIdx.x, tid = threadIdx.x;

  for (int i = tid; i < 768; i += 384) gm[i] = gc_mean[b * 768 + i];
  __syncthreads();

  float z = gp_b1[tid];
  for (int k = 0; k < 768; k++) z += gm[k] * gp_w1[k * 384 + tid];
  float2 s = blk_sum2(z, z * z, red);
  {
    float mean = s.x * (1.f / 384.f);
    float rinv = rsqrtf(s.y * (1.f / 384.f) - mean * mean + 1e-5f);
    float y = (z - mean) * rinv * gp_g1[tid] + gp_be1[tid];
    tmp[tid] = fmaxf(y, 0.f);
  }
  __syncthreads();

  if (tid < 64) {
    float g = gp_b2[tid];
    for (int k = 0; k < 384; k++) g += tmp[k] * gp_w2[k * 64 + tid];
    float sc = (mask[b] != 0) ? 1.0f : 0.1f;
    cxfs[b * 64 + tid] = g * sc;
    cxfu[b * 64 + tid] = g;
    buf[tid] = g;
  }
  for (int i = tid; i < 768; i += 384) buf[64 + i] = qf[b * 768 + i];
  __syncthreads();

  float z1 = 0.f;
  if (tid < 256) {
    z1 = swp_b1[tid];
    for (int k = 0; k < 832; k++) z1 += buf[k] * swp_w1[k * 256 + tid];
  }
  s = blk_sum2(z1, z1 * z1, red);
  {
    float mean = s.x * (1.f / 256.f);
    float rinv = rsqrtf(s.y * (1.f / 256.f) - mean * mean + 1e-5f);
    if (tid < 256) {
      float y = (z1 - mean) * rinv * swp_g1[tid] + swp_be1[tid];
      tmp[tid] = 0.5f * y * (1.f + erff(y * 0.7071067811865476f));
    }
  }
  __syncthreads();

  float z2 = 0.f;
  if (tid < 128) {
    z2 = swp_b2[tid];
    for (int k = 0; k < 256; k++) z2 += tmp[k] * swp_w2[k * 128 + tid];
  }
  s = blk_sum2(z2, z2 * z2, red);
  {
    float mean = s.x * (1.f / 128.f);
    float rinv = rsqrtf(s.y * (1.f / 128.f) - mean * mean + 1e-5f);
    if (tid < 128) {
      float y = (z2 - mean) * rinv * swp_g2[tid] + swp_be2[tid];
      tmp[tid] = 0.5f * y * (1.f + erff(y * 0.7071067811865476f));
    }
  }
  __syncthreads();

  if (tid < 8) {
    float z3 = swp_b3[tid];
    for (int k = 0; k < 128; k++) z3 += tmp[k] * swp_w3[k * 8 + tid];
    buf[tid] = z3;
  }
  __syncthreads();
  if (tid < 8) {
    float mx = buf[0];
    for (int k = 1; k < 8; k++) mx = fmaxf(mx, buf[k]);
    float ssum = 0.f;
    for (int k = 0; k < 8; k++) ssum += expf(buf[k] - mx);
    aw[b * 8 + tid] = expf(buf[tid] - mx) / ssum;
  }
}

// ---------------------------------------------------------------- ctx->bias
__global__ void ctxbias_k(const float* __restrict__ cxfs,
                          const float* __restrict__ cxfu,
                          const float* __restrict__ sw1, const float* __restrict__ rw1,
                          const float* __restrict__ sb1, const float* __restrict__ rb1,
                          float* __restrict__ b1x)
{
  const int br = blockIdx.x, b = blockIdx.y, tid = threadIdx.x;
  __shared__ float cf[64];
  if (tid < 64) cf[tid] = ((br <= 4) ? cxfs : cxfu)[b * 64 + tid];
  __syncthreads();
  const float* W = ((br < 4) ? sw1 + (size_t)br * 832 * DD
                             : rw1 + (size_t)(br - 4) * 832 * DD) + (size_t)768 * DD;
  const float* bb = (br < 4) ? sb1 + br * DD : rb1 + (br - 4) * DD;
#pragma unroll
  for (int jj = 0; jj < 3; ++jj) {
    const int f = tid + jj * 256;
    float s = bb[f];
    for (int k = 0; k < 64; ++k) s += cf[k] * W[(size_t)k * DD + f];
    b1x[((size_t)br * 16 + b) * DD + f] = s;
  }
}

// ---------------------------------------------------------------- stats
__global__ void stats_k(const float2* __restrict__ part, float2* __restrict__ st,
                        int nr) {
  int i = blockIdx.x * 256 + threadIdx.x;
  if (i >= nr) return;
  float s1 = 0.f, s2 = 0.f;
#pragma unroll
  for (int s = 0; s < 3; ++s) {
    float2 p = part[(size_t)s * nr + i];
    s1 += p.x; s2 += p.y;
  }
  float mean = s1 * (1.f / 768.f);
  float var = s2 * (1.f / 768.f) - mean * mean;
  float rinv = rsqrtf(var + 1e-5f);
  st[i] = make_float2(rinv, -mean * rinv);
}

// ================================================================ GEMM1
// R12 + B-pipeline fix: loadA regs FIRST, then issue B(t+2) into 3-slot ring.
// Auto-vmcnt before commitA is now vmcnt(2) (keeps B(t+2) flying); B(t) was
// retired one full iteration before compute(t). LDS 69KB -> 2 blocks/CU.
__global__ __launch_bounds__(512, 4)
void gemm1_k(const float* __restrict__ comps,
             const unsigned short* __restrict__ w1T,
             const float* __restrict__ b1x,
             unsigned short* __restrict__ z1,
             float2* __restrict__ part1,
             const int* __restrict__ mask)
{
  __shared__ __align__(16) unsigned short As[2][4096];
  __shared__ __align__(16) unsigned short Bs[3][8192];
  __shared__ float pscr[4][128][2];
  constexpr int NT = 24;

  const int id = blockIdx.x;
  const int x = id & 7, j = id >> 3;        // j 0..383 per-XCD stream
  const int nt = j % 3;                     // innermost: A-panel reuse
  const int r2 = j / 3;                     // 0..127
  const int br = r2 >> 4;                   // 0..7
  const int mt = ((r2 & 15) << 3) | x;      // 0..127
  const int m0 = mt * 128, n0 = nt * 256;
  const int b = m0 >> 10;
  if (br >= 5 && mask[b] == 0) return;

  const int ci = (0x76245310u >> (br * 4)) & 15;
  const float* afp = comps + (size_t)ci * MT * DD + (size_t)m0 * DD;
  const unsigned short* wT = w1T + (size_t)br * DD * DD + (size_t)n0 * DD;

  const int tid = threadIdx.x;
  const int w = tid >> 6, lane = tid & 63, llo = lane & 15, lhi = lane >> 4;
  const int wm = w & 1, wn = w >> 1;

  // A staging: 1 slot (16B) per thread; write-side swizzle
  const int arow = tid >> 2, ap = tid & 3;
  const int aslot = (arow * 32 + ((ap ^ ((arow >> 1) & 3)) << 3));
  const float* asrc = afp + (size_t)arow * DD + ap * 8;

  // B staging: 2 DMAs per wave, pre-swizzled source
  const int q = lane & 3, rrB = w * 16 + (lane >> 2);
  const int swqB = q ^ ((rrB >> 1) & 3);
  const unsigned short* bsrc0 = wT + (size_t)rrB * DD + swqB * 8;
  const unsigned short* bsrc1 = wT + (size_t)(128 + rrB) * DD + swqB * 8;

  f32x4 acc[4][4];
#pragma unroll
  for (int mf = 0; mf < 4; ++mf)
#pragma unroll
    for (int nf = 0; nf < 4; ++nf) acc[mf][nf] = (f32x4)0.0f;

  struct St { u32x4 q0, q1; };

  auto issueB = [&](int kt, int s) {
    gload_lds16(bsrc0 + (size_t)kt * 32, &Bs[s][w * 512]);
    gload_lds16(bsrc1 + (size_t)kt * 32, &Bs[s][4096 + w * 512]);
  };
  auto loadA = [&](int kt) -> St {
    St s;
    const u32x4* p = (const u32x4*)(asrc + kt * 32);
    s.q0 = p[0]; s.q1 = p[1];
    return s;
  };
  auto commitA = [&](const St& s, int sl) {
    u32x4 v;
    v[0] = pk2(__uint_as_float(s.q0[0]), __uint_as_float(s.q0[1]));
    v[1] = pk2(__uint_as_float(s.q0[2]), __uint_as_float(s.q0[3]));
    v[2] = pk2(__uint_as_float(s.q1[0]), __uint_as_float(s.q1[1]));
    v[3] = pk2(__uint_as_float(s.q1[2]), __uint_as_float(s.q1[3]));
    *(u32x4*)&As[sl][aslot] = v;
  };

  const int aswz = (lhi ^ ((llo >> 1) & 3)) << 3;
  const int arow0 = (wm * 64 + llo) * 32 + aswz;
  const int brow0 = (wn * 64 + llo) * 32 + aswz;
  auto compute = [&](int sa, int sb) {
    short8 afr[4];
#pragma unroll
    for (int mf = 0; mf < 4; ++mf)
      afr[mf] = *(const short8*)&As[sa][arow0 + mf * 512];
#pragma unroll
    for (int nf = 0; nf < 4; ++nf) {
      short8 bfr = *(const short8*)&Bs[sb][brow0 + nf * 512];
#pragma unroll
      for (int mf = 0; mf < 4; ++mf)
        acc[mf][nf] = __builtin_amdgcn_mfma_f32_16x16x32_bf16(afr[mf], bfr, acc[mf][nf], 0, 0, 0);
    }
  };

  // prologue: B(0),B(1) in flight; A(0) committed (one-time full drain)
  issueB(0, 0);
  issueB(1, 1);
  {
    St s0 = loadA(0);
    commitA(s0, 0);                       // auto vmcnt(0): B(0),B(1) also land
  }
  asm volatile("s_waitcnt lgkmcnt(0)" ::: "memory");
  __builtin_amdgcn_sched_barrier(0);
  __builtin_amdgcn_s_barrier();

  int sb = 0;                              // B slot of tile t
#pragma unroll 1
  for (int t = 0; t < NT; ++t) {
    const int sa = t & 1, san = sa ^ 1;
    int sb2 = sb + 2; if (sb2 >= 3) sb2 -= 3;
    St sn;
    if (t + 1 < NT) sn = loadA(t + 1);     // A regs FIRST (oldest)
    if (t + 2 < NT) issueB(t + 2, sb2);    // B issue AFTER A (youngest)
    __builtin_amdgcn_sched_barrier(0);
    compute(sa, sb);
    __builtin_amdgcn_sched_barrier(0);
    if (t + 1 < NT) commitA(sn, san);      // auto vmcnt(2): B(t+2) keeps flying
    asm volatile("s_waitcnt lgkmcnt(0)" ::: "memory");
    __builtin_amdgcn_sched_barrier(0);
    __builtin_amdgcn_s_barrier();
    ++sb; if (sb == 3) sb = 0;
  }

  // epilogue: bias(b1x), z-store bf16, row partials
  const float* bias = b1x + ((size_t)br * 16 + b) * DD;
  unsigned short* zo = z1 + (size_t)br * MT * DD + (size_t)m0 * DD;
  const int n0w = n0 + wn * 64;
  float bia[4];
#pragma unroll
  for (int nf = 0; nf < 4; ++nf) bia[nf] = bias[n0w + nf * 16 + llo];
#pragma unroll
  for (int mf = 0; mf < 4; ++mf) {
#pragma unroll
    for (int r = 0; r < 4; ++r) {
      float zz[4]; float s1v = 0.f, s2v = 0.f;
#pragma unroll
      for (int nf = 0; nf < 4; ++nf) {
        float zv = acc[mf][nf][r] + bia[nf];
        zz[nf] = zv; s1v += zv; s2v += zv * zv;
      }
      const int rloc = wm * 64 + mf * 16 + lhi * 4 + r;
      const size_t rowoff = (size_t)rloc * DD;
#pragma unroll
      for (int nf = 0; nf < 4; ++nf) {
        float zon = __shfl_xor(zz[nf], 1);
        if ((llo & 1) == 0)
          *(unsigned*)&zo[rowoff + n0w + nf * 16 + llo] = pk2(zz[nf], zon);
      }
#pragma unroll
      for (int d = 1; d < 16; d <<= 1) {
        s1v += __shfl_xor(s1v, d); s2v += __shfl_xor(s2v, d);
      }
      if (llo == 0) { pscr[wn][rloc][0] = s1v; pscr[wn][rloc][1] = s2v; }
    }
  }
  __syncthreads();
  if (tid < 128) {
    float a = 0.f, c = 0.f;
#pragma unroll
    for (int qq = 0; qq < 4; ++qq) { a += pscr[qq][tid][0]; c += pscr[qq][tid][1]; }
    part1[(size_t)nt * (8 * MT) + (size_t)br * MT + m0 + tid] = make_float2(a, c);
  }
}

// ---------------------------------------------------------------- act1
__global__ void act1_k(const unsigned short* __restrict__ z1,
                       const float2* __restrict__ st1,
                       const float* __restrict__ sg1, const float* __restrict__ sbe1,
                       const float* __restrict__ rg1, const float* __restrict__ rbe1,
                       const int* __restrict__ mask,
                       unsigned short* __restrict__ a1)
{
  const int tid = threadIdx.x;
  const int rowg = blockIdx.x * 8 + (tid >> 5);   // 0..131071
  const int l = tid & 31;
  const int br = rowg >> 14;
  const int r = rowg & 16383;
  const int b = r >> 10;
  if (br >= 5 && mask[b] == 0) return;
  const bool isg = (br < 4);
  const float* g  = (isg ? sg1  + br * DD : rg1  + (br - 4) * DD);
  const float* be = (isg ? sbe1 + br * DD : rbe1 + (br - 4) * DD);
  const float2 stv = st1[rowg];
  const unsigned short* zp = z1 + (size_t)rowg * DD;
  unsigned short* op = a1 + (size_t)rowg * DD;
#pragma unroll
  for (int c = 0; c < 3; ++c) {
    const int col = l * 8 + c * 256;
    u32x4 zv = *(const u32x4*)(zp + col);
    fv4 ga = *(const fv4*)(g + col), gb = *(const fv4*)(g + col + 4);
    fv4 ba = *(const fv4*)(be + col), bb = *(const fv4*)(be + col + 4);
    float y[8];
#pragma unroll
    for (int wd = 0; wd < 2; ++wd) {
      y[2*wd]   = fmaf(fmaf(bf2f((unsigned short)(zv[wd] & 0xffffu)), stv.x, stv.y), ga[2*wd], ba[2*wd]);
      y[2*wd+1] = fmaf(fmaf(bf2f((unsigned short)(zv[wd] >> 16)), stv.x, stv.y), ga[2*wd+1], ba[2*wd+1]);
      y[4+2*wd]   = fmaf(fmaf(bf2f((unsigned short)(zv[wd+2] & 0xffffu)), stv.x, stv.y), gb[2*wd], bb[2*wd]);
      y[4+2*wd+1] = fmaf(fmaf(bf2f((unsigned short)(zv[wd+2] >> 16)), stv.x, stv.y), gb[2*wd+1], bb[2*wd+1]);
    }
    u32x4 ov;
#pragma unroll
    for (int wd = 0; wd < 4; ++wd) {
      float y0 = y[2*wd], y1 = y[2*wd+1];
      if (isg) { y0 = gelu_t(y0); y1 = gelu_t(y1); }
      else     { y0 = fmaxf(y0, 0.f); y1 = fmaxf(y1, 0.f); }
      ov[wd] = pk2(y0, y1);
    }
    *(u32x4*)(op + col) = ov;
  }
}

// ================================================================ GEMM2
// R11/R12 structure unchanged (already 2-iteration prefetch cover).
__global__ __launch_bounds__(512, 4)
void gemm2_k(const float* __restrict__ comps,
             const unsigned short* __restrict__ a1,
             const unsigned short* __restrict__ w2T,
             const float* __restrict__ sb2, const float* __restrict__ rb2,
             unsigned short* __restrict__ z2,
             float2* __restrict__ part2,
             float* __restrict__ outp,
             const int* __restrict__ mask)
{
  __shared__ __align__(16) unsigned short As[3][4096];
  __shared__ __align__(16) unsigned short Bs[3][8192];
  __shared__ float pscr[4][128][2];
  constexpr int NT = 24;

  const int id = blockIdx.x;
  const int x = id & 7, j = id >> 3;
  const int nt = j % 3;
  const int r2 = j / 3;
  const int br = r2 >> 4;
  const int mt = ((r2 & 15) << 3) | x;
  const int m0 = mt * 128, n0 = nt * 256;
  const int b = m0 >> 10;
  const int ci = (0x76245310u >> (br * 4)) & 15;
  const int tid = threadIdx.x;

  if (br >= 5 && mask[b] == 0) {            // masked: out = comps tile
    const float* cs = comps + (size_t)ci * MT * DD + (size_t)m0 * DD + n0;
    float* cd = outp + (size_t)ci * MT * DD + (size_t)m0 * DD + n0;
#pragma unroll 1
    for (int k = 0; k < 16; ++k) {
      int idx = tid + k * 512;
      int r3 = idx >> 6, c4 = (idx & 63) * 4;
      *(fv4*)(cd + (size_t)r3 * DD + c4) = *(const fv4*)(cs + (size_t)r3 * DD + c4);
    }
    return;
  }

  const unsigned short* az = a1 + (size_t)br * MT * DD + (size_t)m0 * DD;
  const unsigned short* wT = w2T + (size_t)br * DD * DD + (size_t)n0 * DD;

  const int w = tid >> 6, lane = tid & 63, llo = lane & 15, lhi = lane >> 4;
  const int wm = w & 1, wn = w >> 1;
  const int q = lane & 3, rrB = w * 16 + (lane >> 2);
  const int swqB = q ^ ((rrB >> 1) & 3);

  const unsigned short* asrcD = az + (size_t)rrB * DD + swqB * 8;
  const unsigned short* bsrc0 = wT + (size_t)rrB * DD + swqB * 8;
  const unsigned short* bsrc1 = wT + (size_t)(128 + rrB) * DD + swqB * 8;

  f32x4 acc[4][4];
#pragma unroll
  for (int mf = 0; mf < 4; ++mf)
#pragma unroll
    for (int nf = 0; nf < 4; ++nf) acc[mf][nf] = (f32x4)0.0f;

  auto issueT = [&](int kt, int s) {        // 3 DMAs per thread per tile
    gload_lds16(asrcD + (size_t)kt * 32, &As[s][w * 512]);
    gload_lds16(bsrc0 + (size_t)kt * 32, &Bs[s][w * 512]);
    gload_lds16(bsrc1 + (size_t)kt * 32, &Bs[s][4096 + w * 512]);
  };

  const int aswz = (lhi ^ ((llo >> 1) & 3)) << 3;
  const int arow0 = (wm * 64 + llo) * 32 + aswz;
  const int brow0 = (wn * 64 + llo) * 32 + aswz;
  auto compute = [&](int sl) {
    short8 afr[4];
#pragma unroll
    for (int mf = 0; mf < 4; ++mf)
      afr[mf] = *(const short8*)&As[sl][arow0 + mf * 512];
#pragma unroll
    for (int nf = 0; nf < 4; ++nf) {
      short8 bfr = *(const short8*)&Bs[sl][brow0 + nf * 512];
#pragma unroll
      for (int mf = 0; mf < 4; ++mf)
        acc[mf][nf] = __builtin_amdgcn_mfma_f32_16x16x32_bf16(afr[mf], bfr, acc[mf][nf], 0, 0, 0);
    }
  };

  // prologue: tiles 0,1 in flight; wait tile 0 only
  issueT(0, 0);
  issueT(1, 1);
  asm volatile("s_waitcnt vmcnt(3)" ::: "memory");
  __builtin_amdgcn_sched_barrier(0);
  __builtin_amdgcn_s_barrier();

  int sc = 0;
#pragma unroll 1
  for (int t = 0; t < NT; ++t) {
    int s2 = sc + 2; if (s2 >= 3) s2 -= 3;
    const bool more = (t + 2 < NT);
    if (more) issueT(t + 2, s2);
    __builtin_amdgcn_sched_barrier(0);
    compute(sc);
    if (more) asm volatile("s_waitcnt vmcnt(3)" ::: "memory");
    else      asm volatile("s_waitcnt vmcnt(0)" ::: "memory");
    asm volatile("s_waitcnt lgkmcnt(0)" ::: "memory");
    __builtin_amdgcn_sched_barrier(0);
    __builtin_amdgcn_s_barrier();
    ++sc; if (sc == 3) sc = 0;
  }

  // epilogue
  const int n0w = n0 + wn * 64;
  const float* bias = ((br < 4) ? sb2 : rb2) + (br & 3) * DD;
  float bia[4];
#pragma unroll
  for (int nf = 0; nf < 4; ++nf) bia[nf] = bias[n0w + nf * 16 + llo];

  if (br < 4) {
    unsigned short* zo = z2 + (size_t)br * MT * DD + (size_t)m0 * DD;
#pragma unroll
    for (int mf = 0; mf < 4; ++mf) {
#pragma unroll
      for (int r = 0; r < 4; ++r) {
        float zz[4]; float s1v = 0.f, s2v = 0.f;
#pragma unroll
        for (int nf = 0; nf < 4; ++nf) {
          float zv = acc[mf][nf][r] + bia[nf];
          zz[nf] = zv; s1v += zv; s2v += zv * zv;
        }
        const int rloc = wm * 64 + mf * 16 + lhi * 4 + r;
        const size_t rowoff = (size_t)rloc * DD;
#pragma unroll
        for (int nf = 0; nf < 4; ++nf) {
          float zon = __shfl_xor(zz[nf], 1);
          if ((llo & 1) == 0)
            *(unsigned*)&zo[rowoff + n0w + nf * 16 + llo] = pk2(zz[nf], zon);
        }
#pragma unroll
        for (int d = 1; d < 16; d <<= 1) {
          s1v += __shfl_xor(s1v, d); s2v += __shfl_xor(s2v, d);
        }
        if (llo == 0) { pscr[wn][rloc][0] = s1v; pscr[wn][rloc][1] = s2v; }
      }
    }
    __syncthreads();
    if (tid < 128) {
      float a = 0.f, c = 0.f;
#pragma unroll
      for (int qq = 0; qq < 4; ++qq) { a += pscr[qq][tid][0]; c += pscr[qq][tid][1]; }
      part2[(size_t)nt * (4 * MT) + (size_t)br * MT + m0 + tid] = make_float2(a, c);
    }
  } else {
    float* fo = outp + (size_t)ci * MT * DD + (size_t)m0 * DD;
#pragma unroll
    for (int mf = 0; mf < 4; ++mf) {
#pragma unroll
      for (int r = 0; r < 4; ++r) {
        const int rloc = wm * 64 + mf * 16 + lhi * 4 + r;
        const size_t rowoff = (size_t)rloc * DD;
#pragma unroll
        for (int nf = 0; nf < 4; ++nf)
          fo[rowoff + n0w + nf * 16 + llo] = acc[mf][nf][r] + bia[nf];
      }
    }
  }
}

// ---------------------------------------------------------------- finish s
__global__ void finish_s(const unsigned short* __restrict__ z2,
                         const float2* __restrict__ st2,
                         const float* __restrict__ sg2,
                         const float* __restrict__ sbe2,
                         float* __restrict__ outp)
{
  const int tid = threadIdx.x;
  const int rowg = blockIdx.x * 8 + (tid >> 5);     // 0..65535
  const int l = tid & 31;
  const int br = rowg >> 14;
  const int r = rowg & 16383;
  const int ci = (0x5310u >> (br * 4)) & 15;
  const unsigned short* zp = z2 + (size_t)rowg * DD;
  float* op = outp + (size_t)ci * MT * DD + (size_t)r * DD;
  const float2 stv = st2[rowg];
  const float* g = sg2 + br * DD;
  const float* be = sbe2 + br * DD;
#pragma unroll
  for (int c = 0; c < 3; ++c) {
    const int col = l * 8 + c * 256;
    u32x4 zv = *(const u32x4*)(zp + col);
    fv4 ga = *(const fv4*)(g + col), gb = *(const fv4*)(g + col + 4);
    fv4 ba = *(const fv4*)(be + col), bb = *(const fv4*)(be + col + 4);
    fv4 o0, o1;
#pragma unroll
    for (int wd = 0; wd < 2; ++wd) {
      o0[2 * wd]     = fmaf(fmaf(bf2f((unsigned short)(zv[wd] & 0xffffu)), stv.x, stv.y), ga[2 * wd], ba[2 * wd]);
      o0[2 * wd + 1] = fmaf(fmaf(bf2f((unsigned short)(zv[wd] >> 16)), stv.x, stv.y), ga[2 * wd + 1], ba[2 * wd + 1]);
      o1[2 * wd]     = fmaf(fmaf(bf2f((unsigned short)(zv[wd + 2] & 0xffffu)), stv.x, stv.y), gb[2 * wd], bb[2 * wd]);
      o1[2 * wd + 1] = fmaf(fmaf(bf2f((unsigned short)(zv[wd + 2] >> 16)), stv.x, stv.y), gb[2 * wd + 1], bb[2 * wd + 1]);
    }
    *(fv4*)(op + col) = o0;
    *(fv4*)(op + col + 4) = o1;
  }
}

// ---------------------------------------------------------------- launch
extern "C" void kernel_launch(void* const* d_in, const int* in_sizes, int n_in,
                              void* d_out, int out_size, void* d_ws, size_t ws_size,
                              hipStream_t stream)
{
  (void)in_sizes; (void)n_in; (void)out_size; (void)ws_size;
  const float* comps  = (const float*)d_in[0];
  const float* geo    = (const float*)d_in[1];
  const float* qf     = (const float*)d_in[2];
  const int*   mask   = (const int*)d_in[3];
  const float* gp_w1  = (const float*)d_in[4];
  const float* gp_b1  = (const float*)d_in[5];
  const float* gp_g1  = (const float*)d_in[6];
  const float* gp_be1 = (const float*)d_in[7];
  const float* gp_w2  = (const float*)d_in[8];
  const float* gp_b2  = (const float*)d_in[9];
  const float* swp_w1 = (const float*)d_in[10];
  const float* swp_b1 = (const float*)d_in[11];
  const float* swp_g1 = (const float*)d_in[12];
  const float* swp_be1= (const float*)d_in[13];
  const float* swp_w2 = (const float*)d_in[14];
  const float* swp_b2 = (const float*)d_in[15];
  const float* swp_g2 = (const float*)d_in[16];
  const float* swp_be2= (const float*)d_in[17];
  const float* swp_w3 = (const float*)d_in[18];
  const float* swp_b3 = (const float*)d_in[19];
  const float* sw1 = (const float*)d_in[20];
  const float* sb1 = (const float*)d_in[21];
  const float* sg1 = (const float*)d_in[22];
  const float* sbe1= (const float*)d_in[23];
  const float* sw2 = (const float*)d_in[24];
  const float* sb2 = (const float*)d_in[25];
  const float* sg2 = (const float*)d_in[26];
  const float* sbe2= (const float*)d_in[27];
  const float* rw1 = (const float*)d_in[28];
  const float* rb1 = (const float*)d_in[29];
  const float* rg1 = (const float*)d_in[30];
  const float* rbe1= (const float*)d_in[31];
  const float* rw2 = (const float*)d_in[32];
  const float* rb2 = (const float*)d_in[33];
  float* out = (float*)d_out;

  char* ws = (char*)d_ws;
  unsigned short* w1T = (unsigned short*)(ws + OFF_W1T);
  unsigned short* w2T = (unsigned short*)(ws + OFF_W2T);
  unsigned short* z1  = (unsigned short*)(ws + OFF_Z1);
  unsigned short* z2  = (unsigned short*)(ws + OFF_Z2);
  float2* part1 = (float2*)(ws + OFF_P1);
  float2* part2 = (float2*)(ws + OFF_P2);
  float2* st1   = (float2*)(ws + OFF_ST1);
  float2* st2   = (float2*)(ws + OFF_ST2);
  float* gpart  = (float*)(ws + OFF_GP);
  float* gmean  = (float*)(ws + OFF_GM);
  float* cxfs   = (float*)(ws + OFF_CXF);
  float* cxfu   = (float*)(ws + OFF_CXF + 4096);
  float* b1x    = (float*)(ws + OFF_B1X);
  unsigned short* a1 = (unsigned short*)(ws + OFF_A1);

  transpose_cvt<<<dim3(24, 24, 16), 256, 0, stream>>>(sw1, rw1, sw2, rw2, w1T, w2T);
  colmean1<<<dim3(3, 8, 16), 256, 0, stream>>>(geo, gpart);
  colmean2<<<dim3(3, 16), 256, 0, stream>>>(gpart, gmean);
  small_mlp<<<16, 384, 0, stream>>>(gmean, qf, mask,
      gp_w1, gp_b1, gp_g1, gp_be1, gp_w2, gp_b2,
      swp_w1, swp_b1, swp_g1, swp_be1, swp_w2, swp_b2, swp_g2, swp_be2,
      swp_w3, swp_b3, cxfs, cxfu, out + AW_OFF);
  ctxbias_k<<<dim3(8, 16), 256, 0, stream>>>(cxfs, cxfu, sw1, rw1, sb1, rb1, b1x);

  gemm1_k<<<3072, 512, 0, stream>>>(comps, w1T, b1x, z1, part1, mask);
  stats_k<<<512, 256, 0, stream>>>(part1, st1, 8 * MT);
  act1_k<<<16384, 256, 0, stream>>>(z1, st1, sg1, sbe1, rg1, rbe1, mask, a1);
  gemm2_k<<<3072, 512, 0, stream>>>(comps, a1, w2T, sb2, rb2, z2, part2, out, mask);
  stats_k<<<256, 256, 0, stream>>>(part2, st2, 4 * MT);
  finish_s<<<8192, 256, 0, stream>>>(z2, st2, sg2, sbe2, out);
}